// Round 6
// baseline (500.634 us; speedup 1.0000x reference)
//
#include <hip/hip_runtime.h>
#include <hip/hip_bf16.h>
#include <cstdint>
#include <cstddef>

#define N 4096
#define NN ((size_t)N * (size_t)N)

typedef int int4v __attribute__((ext_vector_type(4)));

__device__ inline void async16(const void* g, void* lds) {
    __builtin_amdgcn_global_load_lds(
        (const __attribute__((address_space(1))) void*)g,
        (__attribute__((address_space(3))) void*)lds, 16, 0, 0);
}

// full transcendental path — op-for-op the numpy reference (absmax 0.0, rounds 1-5)
__device__ __noinline__ float mod_full(float p_raw, float uu, float o) {
    float p = fminf(fmaxf(p_raw, 1e-10f), 1.0f - 1e-10f);
    float logits = logf(p) - log1pf(-p);
    float noise  = logf(uu) - log1pf(-uu);
    float y = (logits + noise) / 0.2f;
    float soft = 1.0f / (1.0f + expf(-y));
    float hard = rintf(soft);
    return o + hard * (-2.0f * o);
}

// hybrid: hard = (p+u > 1)  [logit(p)+logit(u) > 0 <=> p+u > 1, exact algebra].
// numpy float32 logit-sum error ~1e-6 maps to |p+u-1| ~ 3e-7; band 1e-5 = 30x safety.
// In-band (~300 of 16.7M elements) takes the proven transcendental path.
__device__ inline float mod_elem(float p_raw, float uu, float o) {
    float p = fmaxf(p_raw, 1e-10f);
    float s = p + uu;
    if (__builtin_expect(fabsf(s - 1.0f) < 1e-5f, 0))
        return mod_full(p_raw, uu, o);
    return (s > 1.0f) ? -o : o;   // o + hard*(-2o), exact
}

// ---------------- kernel 1: fused mod + A-build, 64x64 symmetric tile pairs, 2-launch pipeline ---
// Block (bx<=by): mod for tiles F=(bi,bj) and M=(bj,bi) (each element once) -> out, then
// A[i][j] = mod[i][j]+mod[j][i]-mod[j][j] as i8 into A, AT, |A|, |A|T for both tiles.
// Diagonal mod values computed in-block (no diag kernel). Block (0,0) zeros accs+ticket.
__global__ __launch_bounds__(256) void fused_mod_A(
        const float* __restrict__ ori, const float* __restrict__ clp,
        const float* __restrict__ u, float* __restrict__ out,
        signed char* __restrict__ A, signed char* __restrict__ AT,
        signed char* __restrict__ Aa, signed char* __restrict__ ATa,
        double* __restrict__ accs) {
    const int bx = blockIdx.x, by = blockIdx.y;
    if (bx > by) return;
    const bool dg = (bx == by);
    const int bi = bx * 64, bj = by * 64;
    // stride 65: bank = (c + r) % 32 for both row writes and column reads -> 2 lanes/bank (free)
    __shared__ float mF[64][65];   // mF[r][c] = mod[bi+r][bj+c]
    __shared__ float mM[64][65];   // mM[r][c] = mod[bj+r][bi+c]
    __shared__ float dj_s[64], di_s[64];
    const int t = threadIdx.x;
    if (bx == 0 && by == 0 && t == 0) {
        accs[0] = 0.0; accs[1] = 0.0;
        *(int*)(accs + 2) = 0;     // finalize ticket
    }
    if (t < 64) {
        size_t jj = (size_t)(bj + t) * N + (bj + t);
        dj_s[t] = mod_elem(clp[jj], u[jj], ori[jj]);
    } else if (t < 128) {
        int q = t - 64;
        size_t jj = (size_t)(bi + q) * N + (bi + q);
        di_s[q] = mod_elem(clp[jj], u[jj], ori[jj]);
    }
    const int r = t >> 2;           // 0..63
    const int c16 = (t & 3) << 4;   // 0,16,32,48
    float xF[16], xM[16];
    {
        const size_t base = (size_t)(bi + r) * N + bj + c16;
        #pragma unroll
        for (int q = 0; q < 4; ++q) {
            const size_t idx = base + q * 4;
            float4 p4 = *(const float4*)&clp[idx];
            float4 u4 = *(const float4*)&u[idx];
            float4 o4 = *(const float4*)&ori[idx];
            float4 m4;
            m4.x = mod_elem(p4.x, u4.x, o4.x);
            m4.y = mod_elem(p4.y, u4.y, o4.y);
            m4.z = mod_elem(p4.z, u4.z, o4.z);
            m4.w = mod_elem(p4.w, u4.w, o4.w);
            *(float4*)&out[idx] = m4;
            xF[q * 4 + 0] = m4.x; xF[q * 4 + 1] = m4.y;
            xF[q * 4 + 2] = m4.z; xF[q * 4 + 3] = m4.w;
        }
    }
    if (!dg) {
        const size_t base = (size_t)(bj + r) * N + bi + c16;
        #pragma unroll
        for (int q = 0; q < 4; ++q) {
            const size_t idx = base + q * 4;
            float4 p4 = *(const float4*)&clp[idx];
            float4 u4 = *(const float4*)&u[idx];
            float4 o4 = *(const float4*)&ori[idx];
            float4 m4;
            m4.x = mod_elem(p4.x, u4.x, o4.x);
            m4.y = mod_elem(p4.y, u4.y, o4.y);
            m4.z = mod_elem(p4.z, u4.z, o4.z);
            m4.w = mod_elem(p4.w, u4.w, o4.w);
            *(float4*)&out[idx] = m4;
            xM[q * 4 + 0] = m4.x; xM[q * 4 + 1] = m4.y;
            xM[q * 4 + 2] = m4.z; xM[q * 4 + 3] = m4.w;
        }
    } else {
        #pragma unroll
        for (int k = 0; k < 16; ++k) xM[k] = xF[k];
    }
    #pragma unroll
    for (int k = 0; k < 16; ++k) {
        mF[r][c16 + k] = xF[k];
        mM[r][c16 + k] = xM[k];
    }
    __syncthreads();
    const float djr = dj_s[r], dir = di_s[r];
    int pA[4] = {0,0,0,0}, pAa[4] = {0,0,0,0}, pT[4] = {0,0,0,0}, pTa[4] = {0,0,0,0};
    int qA[4] = {0,0,0,0}, qAa[4] = {0,0,0,0}, qT[4] = {0,0,0,0}, qTa[4] = {0,0,0,0};
    #pragma unroll
    for (int k = 0; k < 16; ++k) {
        const int c = c16 + k;
        const float colF = mF[c][r];   // modF(c,r)
        const float colM = mM[c][r];   // modM(c,r)
        const int w = k >> 2, sh = (k & 3) * 8;
        // A[bi+r][bj+c] = modF(r,c) + modM(c,r) - diag[bj+c]
        int aF = (int)(xF[k] + colM - dj_s[c]);
        // AT[bj+r][bi+c] = A[bi+c][bj+r] = modF(c,r) + modM(r,c) - diag[bj+r]
        int tF = (int)(colF + xM[k] - djr);
        pA [w] |= (aF & 255) << sh;
        pAa[w] |= (aF < 0 ? -aF : aF) << sh;
        pT [w] |= (tF & 255) << sh;
        pTa[w] |= (tF < 0 ? -tF : tF) << sh;
        if (!dg) {
            // A[bj+r][bi+c] = modM(r,c) + modF(c,r) - diag[bi+c]
            int aM = (int)(xM[k] + colF - di_s[c]);
            // AT[bi+r][bj+c] = A[bj+c][bi+r] = modM(c,r) + modF(r,c) - diag[bi+r]
            int tM = (int)(colM + xF[k] - dir);
            qA [w] |= (aM & 255) << sh;
            qAa[w] |= (aM < 0 ? -aM : aM) << sh;
            qT [w] |= (tM & 255) << sh;
            qTa[w] |= (tM < 0 ? -tM : tM) << sh;
        }
    }
    const size_t oF = (size_t)(bi + r) * N + bj + c16;
    const size_t oM = (size_t)(bj + r) * N + bi + c16;
    *(int4*)&A  [oF] = make_int4(pA [0], pA [1], pA [2], pA [3]);
    *(int4*)&Aa [oF] = make_int4(pAa[0], pAa[1], pAa[2], pAa[3]);
    *(int4*)&AT [oM] = make_int4(pT [0], pT [1], pT [2], pT [3]);
    *(int4*)&ATa[oM] = make_int4(pTa[0], pTa[1], pTa[2], pTa[3]);
    if (!dg) {
        *(int4*)&A  [oM] = make_int4(qA [0], qA [1], qA [2], qA [3]);
        *(int4*)&Aa [oM] = make_int4(qAa[0], qAa[1], qAa[2], qAa[3]);
        *(int4*)&AT [oF] = make_int4(qT [0], qT [1], qT [2], qT [3]);
        *(int4*)&ATa[oF] = make_int4(qTa[0], qTa[1], qTa[2], qTa[3]);
    }
}

// ---------------- kernel 2: i8 GEMM-trace, 16x16x64 MFMA, BK=128 (round-3 proven: 0 conflicts),
// with finalize folded in via done-ticket ----------------
__global__ __launch_bounds__(256) void gemm_trace_i8(const signed char* __restrict__ Ag,
                                                     const signed char* __restrict__ ATg,
                                                     const signed char* __restrict__ Aag,
                                                     const signed char* __restrict__ ATag,
                                                     double* __restrict__ accs,
                                                     float* __restrict__ out) {
    __shared__ int4v As4[1024];   // [0..511]=K 0..63, [512..1023]=K 64..127
    __shared__ int4v Bs4[1024];
    __shared__ int red[4];
    const int z = blockIdx.z;
    const signed char* Asrc = z ? Aag  : Ag;    // M rows   (i-panel)
    const signed char* Bsrc = z ? ATag : ATg;   // MT rows  (k-panel), B[k][n] = MT[n][k]
    const int i0 = blockIdx.y * 128;
    const int k0 = blockIdx.x * 128;
    const int t = threadIdx.x;
    const int lane = t & 63;
    const int wave = t >> 6;
    const int quad = lane >> 4;
    const int col  = lane & 15;
    const int wr = (wave >> 1) * 64;
    const int wc = (wave & 1) * 64;
    signed char* Asc = (signed char*)As4;
    signed char* Bsc = (signed char*)Bs4;

    const int r0 = t >> 2;               // 0..63
    const int c0 = (t & 3) ^ ((r0 >> 1) & 3);
    const signed char* gA = Asrc + (size_t)(i0 + r0) * N + c0 * 16;
    const signed char* gB = Bsrc + (size_t)(k0 + r0) * N + c0 * 16;
    const int ldst = t * 16;

    int4v acc[4][4];
    #pragma unroll
    for (int a = 0; a < 4; ++a)
        #pragma unroll
        for (int b = 0; b < 4; ++b)
            acc[a][b] = (int4v){0, 0, 0, 0};

    const int fsw = ((quad ^ ((col >> 1) & 3)) << 4);

    for (int kb = 0; kb < N; kb += 128) {
        __syncthreads();
        const signed char* ga = gA + kb;
        const signed char* gb = gB + kb;
        async16(ga,               Asc + ldst);            // K 0..63,  rows 0..63
        async16(ga + 64 * N,      Asc + 4096  + ldst);    // K 0..63,  rows 64..127
        async16(ga + 64,          Asc + 8192  + ldst);    // K 64..127, rows 0..63
        async16(ga + 64 * N + 64, Asc + 12288 + ldst);    // K 64..127, rows 64..127
        async16(gb,               Bsc + ldst);
        async16(gb + 64 * N,      Bsc + 4096  + ldst);
        async16(gb + 64,          Bsc + 8192  + ldst);
        async16(gb + 64 * N + 64, Bsc + 12288 + ldst);
        __syncthreads();
        int4v af0[4], af1[4], bf0[4], bf1[4];
        #pragma unroll
        for (int tr = 0; tr < 4; ++tr) {
            const int ra = (wr + tr * 16 + col) << 6;
            af0[tr] = *(const int4v*)(Asc + ra + fsw);
            af1[tr] = *(const int4v*)(Asc + 8192 + ra + fsw);
        }
        #pragma unroll
        for (int tc = 0; tc < 4; ++tc) {
            const int rb = (wc + tc * 16 + col) << 6;
            bf0[tc] = *(const int4v*)(Bsc + rb + fsw);
            bf1[tc] = *(const int4v*)(Bsc + 8192 + rb + fsw);
        }
        #pragma unroll
        for (int tr = 0; tr < 4; ++tr)
            #pragma unroll
            for (int tc = 0; tc < 4; ++tc)
                acc[tr][tc] = __builtin_amdgcn_mfma_i32_16x16x64_i8(af0[tr], bf0[tc], acc[tr][tc], 0, 0, 0);
        #pragma unroll
        for (int tr = 0; tr < 4; ++tr)
            #pragma unroll
            for (int tc = 0; tc < 4; ++tc)
                acc[tr][tc] = __builtin_amdgcn_mfma_i32_16x16x64_i8(af1[tr], bf1[tc], acc[tr][tc], 0, 0, 0);
    }

    // trace epilogue: C/D layout col=lane&15, row=quad*4+reg (shape-determined).
    // multiplier M[k,i] = MT[i,k] = Bsrc[i*N + k] (already |.| for z=1). Exact int32.
    int part = 0;
    #pragma unroll
    for (int tr = 0; tr < 4; ++tr) {
        #pragma unroll
        for (int tc = 0; tc < 4; ++tc) {
            const int ib = i0 + wr + tr * 16 + quad * 4;
            const int kk = k0 + wc + tc * 16 + col;
            #pragma unroll
            for (int r = 0; r < 4; ++r)
                part += acc[tr][tc][r] * (int)Bsrc[(size_t)(ib + r) * N + kk];
        }
    }
    #pragma unroll
    for (int off = 32; off > 0; off >>= 1)
        part += __shfl_down(part, off, 64);
    if (lane == 0) red[wave] = part;
    __syncthreads();
    if (t == 0) {
        int tot = red[0] + red[1] + red[2] + red[3];
        atomicAdd(&accs[z], (double)tot);
        __threadfence();
        int* done = (int*)(accs + 2);
        int ticket = atomicAdd(done, 1);
        if (ticket == 32 * 32 * 2 - 1) {
            double t3  = atomicAdd(&accs[0], 0.0);   // device-coherent read
            double t3a = atomicAdd(&accs[1], 0.0);
            out[NN] = (float)(0.5 * (1.0 + t3 / t3a));
        }
    }
}

extern "C" void kernel_launch(void* const* d_in, const int* in_sizes, int n_in,
                              void* d_out, int out_size, void* d_ws, size_t ws_size,
                              hipStream_t stream) {
    const float* ori = (const float*)d_in[0];
    const float* clp = (const float*)d_in[1];
    const float* u   = (const float*)d_in[2];
    float* out = (float*)d_out;
    char* ws = (char*)d_ws;
    signed char* A8   = (signed char*)ws;            // 16 MiB
    signed char* AT8  = (signed char*)(ws + NN);     // 16 MiB
    signed char* Aa8  = (signed char*)(ws + 2 * NN); // 16 MiB
    signed char* ATa8 = (signed char*)(ws + 3 * NN); // 16 MiB
    double*      accs = (double*)(ws + 4 * NN);      // 2 doubles + ticket int

    fused_mod_A<<<dim3(N / 64, N / 64), 256, 0, stream>>>(ori, clp, u, out,
                                                          A8, AT8, Aa8, ATa8, accs);
    gemm_trace_i8<<<dim3(N / 128, N / 128, 2), 256, 0, stream>>>(A8, AT8, Aa8, ATa8, accs, out);
}

// Round 7
// 439.275 us; speedup vs baseline: 1.1397x; 1.1397x over previous
//
#include <hip/hip_runtime.h>
#include <hip/hip_bf16.h>
#include <cstdint>
#include <cstddef>

#define N 4096
#define NN ((size_t)N * (size_t)N)

typedef int int4v __attribute__((ext_vector_type(4)));

__device__ inline void async16(const void* g, void* lds) {
    __builtin_amdgcn_global_load_lds(
        (const __attribute__((address_space(1))) void*)g,
        (__attribute__((address_space(3))) void*)lds, 16, 0, 0);
}

// full transcendental path — op-for-op the numpy reference (absmax 0.0, rounds 1-6)
__device__ __noinline__ float mod_full(float p_raw, float uu, float o) {
    float p = fminf(fmaxf(p_raw, 1e-10f), 1.0f - 1e-10f);
    float logits = logf(p) - log1pf(-p);
    float noise  = logf(uu) - log1pf(-uu);
    float y = (logits + noise) / 0.2f;
    float soft = 1.0f / (1.0f + expf(-y));
    float hard = rintf(soft);
    return o + hard * (-2.0f * o);
}

// hybrid: hard = (p+u > 1)  [logit(p)+logit(u) > 0 <=> p+u > 1, exact algebra].
// numpy float32 logit-sum error ~1e-6 maps to |p+u-1| ~ 3e-7; band 1e-5 = 30x safety.
__device__ inline float mod_elem(float p_raw, float uu, float o) {
    float p = fmaxf(p_raw, 1e-10f);
    float s = p + uu;
    if (__builtin_expect(fabsf(s - 1.0f) < 1e-5f, 0))
        return mod_full(p_raw, uu, o);
    return (s > 1.0f) ? -o : o;   // o + hard*(-2o), exact
}

// ---------------- kernel 1: diagonal mod prepass (float + int) + zero accumulators --------------
__global__ void diag_kernel(const float* __restrict__ ori, const float* __restrict__ clp,
                            const float* __restrict__ u, float* __restrict__ d_f,
                            int* __restrict__ d_i, double* __restrict__ accs) {
    int j = blockIdx.x * blockDim.x + threadIdx.x;  // 4096 threads
    size_t idx = (size_t)j * N + j;
    float m = mod_elem(clp[idx], u[idx], ori[idx]);
    d_f[j] = m;
    d_i[j] = (int)m;                                 // exact: m in {-1,0,1}
    if (blockIdx.x == 0 && threadIdx.x < 2) accs[threadIdx.x] = 0.0;
}

// ---------------- kernel 2: fused mod + S/T/TT build, 64x64 symmetric tile pairs ----------------
// S[i][j] = mod[i][j]+mod[j][i] (symmetric), T = |S - e d^T| = |A|, TT = T^T.
__global__ __launch_bounds__(256) void fused_mod_S(
        const float* __restrict__ ori, const float* __restrict__ clp,
        const float* __restrict__ u, const int* __restrict__ d_i,
        float* __restrict__ out,
        signed char* __restrict__ S, signed char* __restrict__ T,
        signed char* __restrict__ TT) {
    const int bx = blockIdx.x, by = blockIdx.y;
    if (bx > by) return;
    const bool dg = (bx == by);
    const int bi = bx * 64, bj = by * 64;
    // stride 65: bank = (c + r) % 32 on column reads -> 2 lanes/bank (free, m136)
    __shared__ float mF[64][65];   // mF[r][c] = mod[bi+r][bj+c]
    __shared__ float mM[64][65];   // mM[r][c] = mod[bj+r][bi+c]
    __shared__ int dj_i[64], di_i[64];
    const int t = threadIdx.x;
    if (t < 64) dj_i[t] = d_i[bj + t];
    else if (t < 128) di_i[t - 64] = d_i[bi + (t - 64)];
    const int r = t >> 2;           // 0..63
    const int c16 = (t & 3) << 4;   // 0,16,32,48
    float xF[16], xM[16];
    {
        const size_t base = (size_t)(bi + r) * N + bj + c16;
        #pragma unroll
        for (int q = 0; q < 4; ++q) {
            const size_t idx = base + q * 4;
            float4 p4 = *(const float4*)&clp[idx];
            float4 u4 = *(const float4*)&u[idx];
            float4 o4 = *(const float4*)&ori[idx];
            float4 m4;
            m4.x = mod_elem(p4.x, u4.x, o4.x);
            m4.y = mod_elem(p4.y, u4.y, o4.y);
            m4.z = mod_elem(p4.z, u4.z, o4.z);
            m4.w = mod_elem(p4.w, u4.w, o4.w);
            *(float4*)&out[idx] = m4;
            xF[q * 4 + 0] = m4.x; xF[q * 4 + 1] = m4.y;
            xF[q * 4 + 2] = m4.z; xF[q * 4 + 3] = m4.w;
        }
    }
    if (!dg) {
        const size_t base = (size_t)(bj + r) * N + bi + c16;
        #pragma unroll
        for (int q = 0; q < 4; ++q) {
            const size_t idx = base + q * 4;
            float4 p4 = *(const float4*)&clp[idx];
            float4 u4 = *(const float4*)&u[idx];
            float4 o4 = *(const float4*)&ori[idx];
            float4 m4;
            m4.x = mod_elem(p4.x, u4.x, o4.x);
            m4.y = mod_elem(p4.y, u4.y, o4.y);
            m4.z = mod_elem(p4.z, u4.z, o4.z);
            m4.w = mod_elem(p4.w, u4.w, o4.w);
            *(float4*)&out[idx] = m4;
            xM[q * 4 + 0] = m4.x; xM[q * 4 + 1] = m4.y;
            xM[q * 4 + 2] = m4.z; xM[q * 4 + 3] = m4.w;
        }
    } else {
        #pragma unroll
        for (int k = 0; k < 16; ++k) xM[k] = xF[k];
    }
    #pragma unroll
    for (int k = 0; k < 16; ++k) {
        mF[r][c16 + k] = xF[k];
        mM[r][c16 + k] = xM[k];
    }
    __syncthreads();
    const int dir = di_i[r], djr = dj_i[r];
    int pS[4] = {0,0,0,0}, pT[4] = {0,0,0,0}, pTT[4] = {0,0,0,0};
    int qS[4] = {0,0,0,0}, qT[4] = {0,0,0,0}, qTT[4] = {0,0,0,0};
    #pragma unroll
    for (int k = 0; k < 16; ++k) {
        const int c = c16 + k;
        const float colF = mF[c][r];   // modF(c,r)
        const float colM = mM[c][r];   // modM(c,r)
        const int w = k >> 2, sh = (k & 3) * 8;
        // S[bi+r][bj+c] = modF(r,c) + modM(c,r)
        const int sF = (int)(xF[k] + colM);
        int tF  = sF - dj_i[c];  tF  = tF  < 0 ? -tF  : tF;   // T [bi+r][bj+c]
        int ttF = sF - dir;      ttF = ttF < 0 ? -ttF : ttF;  // TT[bi+r][bj+c] = T[bj+c][bi+r]
        pS [w] |= (sF  & 255) << sh;
        pT [w] |= tF  << sh;
        pTT[w] |= ttF << sh;
        if (!dg) {
            // S[bj+r][bi+c] = modM(r,c) + modF(c,r)
            const int sM = (int)(xM[k] + colF);
            int tM  = sM - di_i[c];  tM  = tM  < 0 ? -tM  : tM;   // T [bj+r][bi+c]
            int ttM = sM - djr;      ttM = ttM < 0 ? -ttM : ttM;  // TT[bj+r][bi+c]
            qS [w] |= (sM  & 255) << sh;
            qT [w] |= tM  << sh;
            qTT[w] |= ttM << sh;
        }
    }
    const size_t oF = (size_t)(bi + r) * N + bj + c16;
    const size_t oM = (size_t)(bj + r) * N + bi + c16;
    *(int4*)&S [oF] = make_int4(pS [0], pS [1], pS [2], pS [3]);
    *(int4*)&T [oF] = make_int4(pT [0], pT [1], pT [2], pT [3]);
    *(int4*)&TT[oF] = make_int4(pTT[0], pTT[1], pTT[2], pTT[3]);
    if (!dg) {
        *(int4*)&S [oM] = make_int4(qS [0], qS [1], qS [2], qS [3]);
        *(int4*)&T [oM] = make_int4(qT [0], qT [1], qT [2], qT [3]);
        *(int4*)&TT[oM] = make_int4(qTT[0], qTT[1], qTT[2], qTT[3]);
    }
}

// ---------------- kernel 3: row sums Se[i] = sum_j S[i][j], Sd[i] = sum_j S[i][j]*d[j] ----------
__global__ void rowsums(const signed char* __restrict__ S, const int* __restrict__ d_i,
                        int* __restrict__ Se, int* __restrict__ Sd) {
    const int row = blockIdx.x * 4 + (threadIdx.x >> 6);
    const int lane = threadIdx.x & 63;
    const int* Sr = (const int*)(S + (size_t)row * N);
    int se = 0, sd = 0;
    #pragma unroll
    for (int it = 0; it < 16; ++it) {
        const int idx = it * 64 + lane;          // word 0..1023
        const int w = Sr[idx];
        const int4 dv = *(const int4*)&d_i[idx * 4];
        const int b0 = (int)(signed char)(w);
        const int b1 = (int)(signed char)(w >> 8);
        const int b2 = (int)(signed char)(w >> 16);
        const int b3 = (int)(signed char)(w >> 24);
        se += b0 + b1 + b2 + b3;
        sd += b0 * dv.x + b1 * dv.y + b2 * dv.z + b3 * dv.w;
    }
    #pragma unroll
    for (int off = 32; off > 0; off >>= 1) {
        se += __shfl_down(se, off, 64);
        sd += __shfl_down(sd, off, 64);
    }
    if (lane == 0) { Se[row] = se; Sd[row] = sd; }
}

// ---------------- kernel 4: i8 GEMM-trace, 16x16x64 MFMA, BK=128 (round-3 proven) --------------
// z=0: tr(S^3), S symmetric -> triangular block set (bx<=by), off-diag weight 2.
// z=1: tr(T^3), T=|A| via T rows (A-panel) and TT rows (B-panel + epilogue).
__global__ __launch_bounds__(256) void gemm_trace_i8(const signed char* __restrict__ Sg,
                                                     const signed char* __restrict__ Tg,
                                                     const signed char* __restrict__ TTg,
                                                     double* __restrict__ accs) {
    const int z = blockIdx.z;
    if (z == 0 && blockIdx.x > blockIdx.y) return;
    __shared__ int4v As4[1024];   // [0..511]=K 0..63, [512..1023]=K 64..127
    __shared__ int4v Bs4[1024];
    __shared__ int red[4];
    const signed char* Asrc = z ? Tg  : Sg;   // M rows (i-panel)
    const signed char* Bsrc = z ? TTg : Sg;   // MT rows (k-panel); S^T = S
    const int i0 = blockIdx.y * 128;
    const int k0 = blockIdx.x * 128;
    const int t = threadIdx.x;
    const int lane = t & 63;
    const int wave = t >> 6;
    const int quad = lane >> 4;
    const int col  = lane & 15;
    const int wr = (wave >> 1) * 64;
    const int wc = (wave & 1) * 64;
    signed char* Asc = (signed char*)As4;
    signed char* Bsc = (signed char*)Bs4;

    const int r0 = t >> 2;               // 0..63
    const int c0 = (t & 3) ^ ((r0 >> 1) & 3);
    const signed char* gA = Asrc + (size_t)(i0 + r0) * N + c0 * 16;
    const signed char* gB = Bsrc + (size_t)(k0 + r0) * N + c0 * 16;
    const int ldst = t * 16;

    int4v acc[4][4];
    #pragma unroll
    for (int a = 0; a < 4; ++a)
        #pragma unroll
        for (int b = 0; b < 4; ++b)
            acc[a][b] = (int4v){0, 0, 0, 0};

    const int fsw = ((quad ^ ((col >> 1) & 3)) << 4);

    for (int kb = 0; kb < N; kb += 128) {
        __syncthreads();
        const signed char* ga = gA + kb;
        const signed char* gb = gB + kb;
        async16(ga,               Asc + ldst);            // K 0..63,  rows 0..63
        async16(ga + 64 * N,      Asc + 4096  + ldst);    // K 0..63,  rows 64..127
        async16(ga + 64,          Asc + 8192  + ldst);    // K 64..127, rows 0..63
        async16(ga + 64 * N + 64, Asc + 12288 + ldst);    // K 64..127, rows 64..127
        async16(gb,               Bsc + ldst);
        async16(gb + 64 * N,      Bsc + 4096  + ldst);
        async16(gb + 64,          Bsc + 8192  + ldst);
        async16(gb + 64 * N + 64, Bsc + 12288 + ldst);
        __syncthreads();
        int4v af0[4], af1[4], bf0[4], bf1[4];
        #pragma unroll
        for (int tr = 0; tr < 4; ++tr) {
            const int ra = (wr + tr * 16 + col) << 6;
            af0[tr] = *(const int4v*)(Asc + ra + fsw);
            af1[tr] = *(const int4v*)(Asc + 8192 + ra + fsw);
        }
        #pragma unroll
        for (int tc = 0; tc < 4; ++tc) {
            const int rb = (wc + tc * 16 + col) << 6;
            bf0[tc] = *(const int4v*)(Bsc + rb + fsw);
            bf1[tc] = *(const int4v*)(Bsc + 8192 + rb + fsw);
        }
        #pragma unroll
        for (int tr = 0; tr < 4; ++tr)
            #pragma unroll
            for (int tc = 0; tc < 4; ++tc)
                acc[tr][tc] = __builtin_amdgcn_mfma_i32_16x16x64_i8(af0[tr], bf0[tc], acc[tr][tc], 0, 0, 0);
        #pragma unroll
        for (int tr = 0; tr < 4; ++tr)
            #pragma unroll
            for (int tc = 0; tc < 4; ++tc)
                acc[tr][tc] = __builtin_amdgcn_mfma_i32_16x16x64_i8(af1[tr], bf1[tc], acc[tr][tc], 0, 0, 0);
    }

    // epilogue: C/D layout col=lane&15, row=quad*4+reg. multiplier M[k,i] = Bsrc[i*N + k]
    // (z=0: S[i,k]=S[k,i]; z=1: TT[i,k]=T[k,i]). Exact int32.
    int part = 0;
    #pragma unroll
    for (int tr = 0; tr < 4; ++tr) {
        #pragma unroll
        for (int tc = 0; tc < 4; ++tc) {
            const int ib = i0 + wr + tr * 16 + quad * 4;
            const int kk = k0 + wc + tc * 16 + col;
            #pragma unroll
            for (int r = 0; r < 4; ++r)
                part += acc[tr][tc][r] * (int)Bsrc[(size_t)(ib + r) * N + kk];
        }
    }
    #pragma unroll
    for (int off = 32; off > 0; off >>= 1)
        part += __shfl_down(part, off, 64);
    if (lane == 0) red[wave] = part;
    __syncthreads();
    if (t == 0) {
        const int tot = red[0] + red[1] + red[2] + red[3];
        const double wgt = (z == 0 && blockIdx.x != blockIdx.y) ? 2.0 : 1.0;
        atomicAdd(&accs[z], (double)tot * wgt);
    }
}

// ---------------- kernel 5: rank-1 corrections + balance ----------------
// tr(A^3) = tr(S^3) - 3 (Sd).(Se) + 3 (d.e)(d.Se) - (d.e)^3
__global__ void finalize_kernel(const double* __restrict__ accs, const int* __restrict__ d_i,
                                const int* __restrict__ Se, const int* __restrict__ Sd,
                                float* __restrict__ out) {
    __shared__ long long s1[256], s2[256];
    __shared__ int s3[256];
    const int t = threadIdx.x;
    long long a1 = 0, a2 = 0;
    int a3 = 0;
    for (int i = t; i < N; i += 256) {
        const long long se = Se[i];
        a1 += (long long)Sd[i] * se;
        a2 += (long long)d_i[i] * se;
        a3 += d_i[i];
    }
    s1[t] = a1; s2[t] = a2; s3[t] = a3;
    __syncthreads();
    if (t == 0) {
        long long d1 = 0, d2 = 0, sumd = 0;
        for (int i = 0; i < 256; ++i) { d1 += s1[i]; d2 += s2[i]; sumd += s3[i]; }
        const double corr = -3.0 * (double)d1 + 3.0 * (double)sumd * (double)d2
                            - (double)(sumd * sumd * sumd);
        const double tr3 = accs[0] + corr;
        out[NN] = (float)(0.5 * (1.0 + tr3 / accs[1]));
    }
}

extern "C" void kernel_launch(void* const* d_in, const int* in_sizes, int n_in,
                              void* d_out, int out_size, void* d_ws, size_t ws_size,
                              hipStream_t stream) {
    const float* ori = (const float*)d_in[0];
    const float* clp = (const float*)d_in[1];
    const float* u   = (const float*)d_in[2];
    float* out = (float*)d_out;
    char* ws = (char*)d_ws;
    signed char* S8  = (signed char*)ws;             // 16 MiB
    signed char* T8  = (signed char*)(ws + NN);      // 16 MiB
    signed char* TT8 = (signed char*)(ws + 2 * NN);  // 16 MiB
    float* d_f = (float*)(ws + 3 * NN);              // 16 KiB
    int*   d_i = (int*)  (ws + 3 * NN + 16384);      // 16 KiB
    int*   Se  = (int*)  (ws + 3 * NN + 32768);      // 16 KiB
    int*   Sd  = (int*)  (ws + 3 * NN + 49152);      // 16 KiB
    double* accs = (double*)(ws + 3 * NN + 65536);   // 16 B

    diag_kernel<<<dim3(16), 256, 0, stream>>>(ori, clp, u, d_f, d_i, accs);
    fused_mod_S<<<dim3(N / 64, N / 64), 256, 0, stream>>>(ori, clp, u, d_i, out, S8, T8, TT8);
    rowsums<<<dim3(N / 4), 256, 0, stream>>>(S8, d_i, Se, Sd);
    gemm_trace_i8<<<dim3(N / 128, N / 128, 2), 256, 0, stream>>>(S8, T8, TT8, accs);
    finalize_kernel<<<1, 256, 0, stream>>>(accs, d_i, Se, Sd, out);
}